// Round 2
// 637.424 us; speedup vs baseline: 1.2001x; 1.2001x over previous
//
#include <hip/hip_runtime.h>
#include <math.h>

// Problem constants
#define B_    128
#define R_    1152
#define C_    10
#define O_    16
#define I_    338
#define CO_   160          // C_*O_
#define SLAB  20480        // B_*CO_  (one r-slab of u_hat, contiguous)
#define RS_CHUNKS 16
#define R_PER_CHUNK 72     // 1152/16

// ---- uhat MFMA tiling ----
#define KT32   32          // fp32 K-elements per tile (one 16x16x32 MFMA K-span)
#define NKT32  11          // ceil(338/32)
#define TAIL   18          // 338 - 10*32 valid elements in last tile
#define LROW   40          // LDS row stride in ushorts: 32 k + 8 pad (80B rows)

typedef __attribute__((ext_vector_type(8))) short bf16x8;  // 8 bf16 = 4 VGPR (MFMA A/B frag)
typedef __attribute__((ext_vector_type(4))) float f32x4;   // MFMA C/D frag

__device__ __forceinline__ unsigned short bf16_rne(float f) {
    unsigned int u = __float_as_uint(f);
    return (unsigned short)((u + 0x7fffu + ((u >> 16) & 1u)) >> 16);
}
// 3-term split, all RNE: f = h + m + l + eps, |eps| <= 2^-27 |f|.
// With the 6 leading cross-products kept, dropped terms <= 2^-26|x·w| --
// below fp32 fma noise, so u_hat is numerically equivalent to the fp32 GEMM.
__device__ __forceinline__ void cvt_split3(float f, unsigned short* h,
                                           unsigned short* m, unsigned short* l) {
    unsigned short hb = bf16_rne(f);
    float fh = __uint_as_float(((unsigned int)hb) << 16);
    float r1 = f - fh;
    unsigned short mb = bf16_rne(r1);
    float fm = __uint_as_float(((unsigned int)mb) << 16);
    float r2 = r1 - fm;
    unsigned short lb = bf16_rne(r2);
    *h = hb; *m = mb; *l = lb;
}

// ---------------------------------------------------------------------------
// u_hat[b,r,c,o] = sum_i W[r,c,o,i] * x[b,r,i]
// One block per r: M=128(b) x N=160(c*16+o) x K=338 GEMM via 3-term split-bf16
// MFMA:  x*w ~= xh*wh + xh*wm + xm*wh + xh*wl + xm*wm + xl*wh
// (fp32 accumulation in MFMA AGPRs; error below fp32-fma class)
// 4 waves; wave w owns b-rows [32w, 32w+32), all 160 co columns:
//   2 Mtiles x 10 Ntiles of 16x16, 6 MFMAs per tile per 32-K step.
// u layout unchanged: u[r*SLAB + b*160 + c*16 + o]
// ---------------------------------------------------------------------------
__global__ __launch_bounds__(256, 2) void uhat_kernel(const float* __restrict__ x,
                                                      const float* __restrict__ W,
                                                      float* __restrict__ u) {
    __shared__ __align__(16) unsigned short xh[128 * LROW];
    __shared__ __align__(16) unsigned short xm[128 * LROW];
    __shared__ __align__(16) unsigned short xl[128 * LROW];
    __shared__ __align__(16) unsigned short wh[160 * LROW];
    __shared__ __align__(16) unsigned short wm[160 * LROW];
    __shared__ __align__(16) unsigned short wl[160 * LROW];

    const int r    = blockIdx.x;
    const int tid  = threadIdx.x;
    const int lane = tid & 63;
    const int w    = tid >> 6;          // wave 0..3
    const int lr   = lane & 15;         // M-row (A) / N-col (B) / D-col
    const int kq8  = (lane >> 4) * 8;   // this lane's 8-element K-run

    f32x4 acc[2][10];
#pragma unroll
    for (int mt = 0; mt < 2; ++mt)
#pragma unroll
        for (int n = 0; n < 10; ++n) acc[mt][n] = (f32x4){0.f, 0.f, 0.f, 0.f};

    const float* xr = x + (size_t)r * I_;            // + b*(R_*I_) per b-row
    const float* wr = W + (size_t)r * (CO_ * I_);    // + co*I_ per co-row

    for (int kt = 0; kt < NKT32; ++kt) {
        const int k0 = kt * KT32;
        if (kt != NKT32 - 1) {
            // ---- stage x tile: 128 rows x 32 fp32, float4 chunks (q = b*8 + kq) ----
#pragma unroll
            for (int it = 0; it < 4; ++it) {            // 4*256 = 1024 chunks
                int q = tid + it * 256;
                int b = q >> 3, kq = q & 7;
                const float* src = xr + (size_t)b * (R_ * I_) + k0 + kq * 4;
                float4 f = *(const float4*)src;
                ushort4 hv, mv, lv;
                cvt_split3(f.x, &hv.x, &mv.x, &lv.x);
                cvt_split3(f.y, &hv.y, &mv.y, &lv.y);
                cvt_split3(f.z, &hv.z, &mv.z, &lv.z);
                cvt_split3(f.w, &hv.w, &mv.w, &lv.w);
                *(ushort4*)&xh[b * LROW + kq * 4] = hv;
                *(ushort4*)&xm[b * LROW + kq * 4] = mv;
                *(ushort4*)&xl[b * LROW + kq * 4] = lv;
            }
            // ---- stage W tile: 160 rows x 32 fp32 ----
#pragma unroll
            for (int it = 0; it < 5; ++it) {            // 5*256 = 1280 chunks
                int q = tid + it * 256;
                int co = q >> 3, kq = q & 7;
                const float* src = wr + (size_t)co * I_ + k0 + kq * 4;
                float4 f = *(const float4*)src;
                ushort4 hv, mv, lv;
                cvt_split3(f.x, &hv.x, &mv.x, &lv.x);
                cvt_split3(f.y, &hv.y, &mv.y, &lv.y);
                cvt_split3(f.z, &hv.z, &mv.z, &lv.z);
                cvt_split3(f.w, &hv.w, &mv.w, &lv.w);
                *(ushort4*)&wh[co * LROW + kq * 4] = hv;
                *(ushort4*)&wm[co * LROW + kq * 4] = mv;
                *(ushort4*)&wl[co * LROW + kq * 4] = lv;
            }
        } else {
            // ---- tail tile: only first TAIL=18 k valid, zero-pad to 32 ----
#pragma unroll
            for (int it = 0; it < 4; ++it) {
                int q = tid + it * 256;
                int b = q >> 3, kq = q & 7;
                const float* src = xr + (size_t)b * (R_ * I_) + k0;
                unsigned short hv[4], mv[4], lv[4];
#pragma unroll
                for (int j = 0; j < 4; ++j) {
                    int kk = kq * 4 + j;
                    float f = (kk < TAIL) ? src[kk] : 0.f;
                    cvt_split3(f, &hv[j], &mv[j], &lv[j]);
                }
                *(ushort4*)&xh[b * LROW + kq * 4] = make_ushort4(hv[0], hv[1], hv[2], hv[3]);
                *(ushort4*)&xm[b * LROW + kq * 4] = make_ushort4(mv[0], mv[1], mv[2], mv[3]);
                *(ushort4*)&xl[b * LROW + kq * 4] = make_ushort4(lv[0], lv[1], lv[2], lv[3]);
            }
#pragma unroll
            for (int it = 0; it < 5; ++it) {
                int q = tid + it * 256;
                int co = q >> 3, kq = q & 7;
                const float* src = wr + (size_t)co * I_ + k0;
                unsigned short hv[4], mv[4], lv[4];
#pragma unroll
                for (int j = 0; j < 4; ++j) {
                    int kk = kq * 4 + j;
                    float f = (kk < TAIL) ? src[kk] : 0.f;
                    cvt_split3(f, &hv[j], &mv[j], &lv[j]);
                }
                *(ushort4*)&wh[co * LROW + kq * 4] = make_ushort4(hv[0], hv[1], hv[2], hv[3]);
                *(ushort4*)&wm[co * LROW + kq * 4] = make_ushort4(mv[0], mv[1], mv[2], mv[3]);
                *(ushort4*)&wl[co * LROW + kq * 4] = make_ushort4(lv[0], lv[1], lv[2], lv[3]);
            }
        }
        __syncthreads();

        // ---- MFMA: 2 Mtiles x 10 Ntiles, 6 products per tile ----
        bf16x8 ah[2], am[2], al[2];
#pragma unroll
        for (int mt = 0; mt < 2; ++mt) {
            int row = w * 32 + mt * 16 + lr;
            ah[mt] = *(const bf16x8*)&xh[row * LROW + kq8];
            am[mt] = *(const bf16x8*)&xm[row * LROW + kq8];
            al[mt] = *(const bf16x8*)&xl[row * LROW + kq8];
        }
#pragma unroll
        for (int n = 0; n < 10; ++n) {
            int co = n * 16 + lr;
            bf16x8 bh = *(const bf16x8*)&wh[co * LROW + kq8];
            bf16x8 bm = *(const bf16x8*)&wm[co * LROW + kq8];
            bf16x8 bl = *(const bf16x8*)&wl[co * LROW + kq8];
#pragma unroll
            for (int mt = 0; mt < 2; ++mt) {
                acc[mt][n] = __builtin_amdgcn_mfma_f32_16x16x32_bf16(ah[mt], bh, acc[mt][n], 0, 0, 0);
                acc[mt][n] = __builtin_amdgcn_mfma_f32_16x16x32_bf16(ah[mt], bm, acc[mt][n], 0, 0, 0);
                acc[mt][n] = __builtin_amdgcn_mfma_f32_16x16x32_bf16(am[mt], bh, acc[mt][n], 0, 0, 0);
                acc[mt][n] = __builtin_amdgcn_mfma_f32_16x16x32_bf16(ah[mt], bl, acc[mt][n], 0, 0, 0);
                acc[mt][n] = __builtin_amdgcn_mfma_f32_16x16x32_bf16(am[mt], bm, acc[mt][n], 0, 0, 0);
                acc[mt][n] = __builtin_amdgcn_mfma_f32_16x16x32_bf16(al[mt], bh, acc[mt][n], 0, 0, 0);
            }
        }
        __syncthreads();
    }

    // ---- epilogue: D[row][col]: col = lane&15, row = (lane>>4)*4 + reg ----
    float* ur = u + (size_t)r * SLAB;
    const int rquad = (lane >> 4) * 4;
#pragma unroll
    for (int mt = 0; mt < 2; ++mt)
#pragma unroll
        for (int n = 0; n < 10; ++n)
#pragma unroll
            for (int reg = 0; reg < 4; ++reg) {
                int b = w * 32 + mt * 16 + rquad + reg;
                ur[b * CO_ + n * 16 + lr] = acc[mt][n][reg];
            }
}

// ---------------------------------------------------------------------------
// softmax over routes (axis r) per capsule c:  c_ij[r,c] = softmax_r(b_ij[r,c])
// ---------------------------------------------------------------------------
__global__ void softmax_kernel(const float* __restrict__ bij, float* __restrict__ cij) {
    const int c   = blockIdx.x;
    const int tid = threadIdx.x;
    __shared__ float redm[4];
    __shared__ float reds[4];
    __shared__ float bcast[2];

    float m = -1e30f;
    for (int r = tid; r < R_; r += 256) m = fmaxf(m, bij[r * C_ + c]);
#pragma unroll
    for (int off = 32; off > 0; off >>= 1) m = fmaxf(m, __shfl_down(m, off));
    if ((tid & 63) == 0) redm[tid >> 6] = m;
    __syncthreads();
    if (tid == 0) bcast[0] = fmaxf(fmaxf(redm[0], redm[1]), fmaxf(redm[2], redm[3]));
    __syncthreads();
    m = bcast[0];

    float s = 0.f;
    for (int r = tid; r < R_; r += 256) s += expf(bij[r * C_ + c] - m);
#pragma unroll
    for (int off = 32; off > 0; off >>= 1) s += __shfl_down(s, off);
    if ((tid & 63) == 0) reds[tid >> 6] = s;
    __syncthreads();
    if (tid == 0) bcast[1] = reds[0] + reds[1] + reds[2] + reds[3];
    __syncthreads();
    const float inv = 1.0f / bcast[1];
    for (int r = tid; r < R_; r += 256) cij[r * C_ + c] = expf(bij[r * C_ + c] - m) * inv;
}

// ---------------------------------------------------------------------------
// partial s over an r-chunk: partial[chunk, idx] = sum_{r in chunk} c_ij[r,c]*u[r,idx]
// ---------------------------------------------------------------------------
__global__ void v_partial_kernel(const float* __restrict__ u, const float* __restrict__ cij,
                                 float* __restrict__ partial) {
    const int idx   = blockIdx.x * 256 + threadIdx.x;   // 0..20479
    const int chunk = blockIdx.y;
    const int c     = (idx >> 4) % 10;
    const int r0    = chunk * R_PER_CHUNK;
    const float* up = u + (size_t)r0 * SLAB + idx;
    const float* cp = cij + r0 * C_ + c;
    float s = 0.f;
#pragma unroll 4
    for (int rr = 0; rr < R_PER_CHUNK; ++rr)
        s = fmaf(cp[rr * C_], up[(size_t)rr * SLAB], s);
    partial[chunk * SLAB + idx] = s;
}

// sum partials -> s -> squash -> v  (v = s*|s|/(1+s^2), identical to ref formula)
__global__ void v_finalize_kernel(const float* __restrict__ partial, float* __restrict__ v) {
    const int idx = blockIdx.x * 256 + threadIdx.x;
    float s = 0.f;
#pragma unroll
    for (int ch = 0; ch < RS_CHUNKS; ++ch) s += partial[ch * SLAB + idx];
    v[idx] = s * fabsf(s) / (1.0f + s * s);
}

// ---------------------------------------------------------------------------
// agreement: b_ij[r,c] += (1/B) * sum_{b,o} u[r,b,c,o] * v[b,c,o]
// ---------------------------------------------------------------------------
__global__ void agree_kernel(const float* __restrict__ u, const float* __restrict__ v,
                             float* __restrict__ bij) {
    const int r = blockIdx.x;
    const int l = threadIdx.x;   // 0..63
    const int c = threadIdx.y;   // 0..9
    const float* ur = u + (size_t)r * SLAB;
    float acc = 0.f;
#pragma unroll 4
    for (int k = l; k < B_ * O_; k += 64) {
        int b = k >> 4, o = k & 15;
        int off = b * CO_ + c * O_ + o;
        acc = fmaf(ur[off], v[off], acc);
    }
#pragma unroll
    for (int off = 32; off > 0; off >>= 1) acc += __shfl_down(acc, off);
    if (l == 0) bij[r * C_ + c] += acc * (1.0f / B_);
}

// ---------------------------------------------------------------------------
extern "C" void kernel_launch(void* const* d_in, const int* in_sizes, int n_in,
                              void* d_out, int out_size, void* d_ws, size_t ws_size,
                              hipStream_t stream) {
    const float* x = (const float*)d_in[0];   // (B,R,I)
    const float* W = (const float*)d_in[1];   // (R,C,O,I)
    float* out = (float*)d_out;               // (B,C,O,1) = 20480 floats

    // workspace carve-up (floats): ~96 MB total
    float* ws      = (float*)d_ws;
    float* u       = ws;                                 // R_*SLAB = 23,592,960
    float* bij     = u + (size_t)R_ * SLAB;              // 11,520
    float* cij     = bij + R_ * C_;                      // 11,520
    float* partial = cij + R_ * C_;                      // 16*20480
    float* v       = partial + RS_CHUNKS * SLAB;         // 20,480

    hipMemsetAsync(bij, 0, R_ * C_ * sizeof(float), stream);
    uhat_kernel<<<R_, 256, 0, stream>>>(x, W, u);

    for (int it = 0; it < 3; ++it) {
        softmax_kernel<<<C_, 256, 0, stream>>>(bij, cij);
        dim3 g(SLAB / 256, RS_CHUNKS);
        v_partial_kernel<<<g, 256, 0, stream>>>(u, cij, partial);
        float* vout = (it == 2) ? out : v;
        v_finalize_kernel<<<SLAB / 256, 256, 0, stream>>>(partial, vout);
        if (it < 2) agree_kernel<<<R_, dim3(64, 10), 0, stream>>>(u, v, bij);
    }
}